// Round 1
// baseline (2262.654 us; speedup 1.0000x reference)
//
#include <hip/hip_runtime.h>

#define D 64
#define LN_EPS 1e-5f
#define ALPHA 0.5f

// ---------------- Stage 1: WzUx = nf * (z@W.T + deg*(x@U.T + Ub)) ----------
__global__ __launch_bounds__(256) void wzux_kernel(
    const float* __restrict__ z, const float* __restrict__ x,
    const float* __restrict__ nf, const float* __restrict__ W,
    const float* __restrict__ Uw, const float* __restrict__ Ub,
    float* __restrict__ wzux, int N)
{
    // Wsm[d][k], pad row to 65 so Wsm[lane*65+k] is bank-conflict-free
    __shared__ float Wsm[D * 65];
    __shared__ float Usm[D * 65];
    for (int i = threadIdx.x; i < D * D; i += blockDim.x) {
        Wsm[(i >> 6) * 65 + (i & 63)] = W[i];
        Usm[(i >> 6) * 65 + (i & 63)] = Uw[i];
    }
    __syncthreads();

    const int lane = threadIdx.x & 63;
    const int wid  = threadIdx.x >> 6;
    const float ub = Ub[lane];
    const float* wr = &Wsm[lane * 65];
    const float* ur = &Usm[lane * 65];

    for (int n = blockIdx.x * 4 + wid; n < N; n += gridDim.x * 4) {
        float nfv = nf[n];
        float deg = (nfv > 0.f) ? (1.f / nfv) : 0.f;
        float zv = z[n * D + lane];
        float xv = x[n * D + lane];
        float accw = 0.f, accu = 0.f;
#pragma unroll
        for (int k = 0; k < D; ++k) {
            float zk = __shfl(zv, k);
            float xk = __shfl(xv, k);
            accw = fmaf(zk, wr[k], accw);
            accu = fmaf(xk, ur[k], accu);
        }
        wzux[n * D + lane] = nfv * (accw + deg * (accu + ub));
    }
}

// ---------------- Stage 2: per-edge relu+LayerNorm, scatter-add ------------
// 16 lanes per edge, float4 per lane.
__global__ __launch_bounds__(256) void edge_kernel(
    const float4* __restrict__ wzux4,
    const int* __restrict__ row, const int* __restrict__ col,
    const float* __restrict__ nf,
    const float4* __restrict__ gamma4, const float4* __restrict__ beta4,
    float* __restrict__ acc, int E)
{
    int gid = blockIdx.x * blockDim.x + threadIdx.x;
    int eid = gid >> 4;
    if (eid >= E) return;
    int g = gid & 15;

    int r = row[eid];
    int c = col[eid];

    float4 a = wzux4[r * 16 + g];
    float4 b = wzux4[c * 16 + g];
    float e0 = fmaxf(a.x - b.x, 0.f);
    float e1 = fmaxf(a.y - b.y, 0.f);
    float e2 = fmaxf(a.z - b.z, 0.f);
    float e3 = fmaxf(a.w - b.w, 0.f);

    float s  = e0 + e1 + e2 + e3;
    float sq = e0 * e0 + e1 * e1 + e2 * e2 + e3 * e3;
#pragma unroll
    for (int off = 1; off < 16; off <<= 1) {
        s  += __shfl_xor(s, off);
        sq += __shfl_xor(sq, off);
    }
    float mu   = s * (1.f / 64.f);
    float var  = sq * (1.f / 64.f) - mu * mu;
    float rstd = rsqrtf(var + LN_EPS);

    float nfr = nf[r];
    float nfc = nf[c];
    float4 gm = gamma4[g];
    float4 bt = beta4[g];

    float v0 = (e0 - mu) * rstd * gm.x + bt.x;
    float v1 = (e1 - mu) * rstd * gm.y + bt.y;
    float v2 = (e2 - mu) * rstd * gm.z + bt.z;
    float v3 = (e3 - mu) * rstd * gm.w + bt.w;

    float* pr = &acc[r * 64 + g * 4];
    float* pc = &acc[c * 64 + g * 4];
    atomicAdd(pr + 0,  v0 * nfr);
    atomicAdd(pr + 1,  v1 * nfr);
    atomicAdd(pr + 2,  v2 * nfr);
    atomicAdd(pr + 3,  v3 * nfr);
    atomicAdd(pc + 0, -v0 * nfc);
    atomicAdd(pc + 1, -v1 * nfc);
    atomicAdd(pc + 2, -v2 * nfc);
    atomicAdd(pc + 3, -v3 * nfc);
}

// ---------------- Stage 3: out = ALPHA*(-(acc@W)) + (1-ALPHA)*z ------------
// Reads acc (== d_out accumulator) and overwrites d_out in place.
// Safe: each wave owns one node row; the wave-wide load of its row completes
// before the wave's store instruction issues (wave-synchronous execution).
__global__ __launch_bounds__(256) void out_kernel(
    const float* __restrict__ accv, const float* __restrict__ z,
    const float* __restrict__ W, float* __restrict__ out, int N)
{
    // Wsm[k][d]; lane reads Wsm[k*65+lane]: consecutive addrs -> conflict-free
    __shared__ float Wsm[D * 65];
    for (int i = threadIdx.x; i < D * D; i += blockDim.x) {
        Wsm[(i >> 6) * 65 + (i & 63)] = W[i];
    }
    __syncthreads();

    const int lane = threadIdx.x & 63;
    const int wid  = threadIdx.x >> 6;

    for (int n = blockIdx.x * 4 + wid; n < N; n += gridDim.x * 4) {
        float nv = accv[n * D + lane];
        float acc = 0.f;
#pragma unroll
        for (int k = 0; k < D; ++k) {
            float nk = __shfl(nv, k);
            acc = fmaf(nk, Wsm[k * 65 + lane], acc);
        }
        out[n * D + lane] = (1.0f - ALPHA) * z[n * D + lane] - ALPHA * acc;
    }
}

extern "C" void kernel_launch(void* const* d_in, const int* in_sizes, int n_in,
                              void* d_out, int out_size, void* d_ws, size_t ws_size,
                              hipStream_t stream) {
    const float* z     = (const float*)d_in[0];
    const float* x     = (const float*)d_in[1];
    const int*   ei    = (const int*)d_in[2];
    const float* nf    = (const float*)d_in[3];
    const float* W     = (const float*)d_in[4];
    const float* Uw    = (const float*)d_in[5];
    const float* Ub    = (const float*)d_in[6];
    const float* gamma = (const float*)d_in[7];
    const float* beta  = (const float*)d_in[8];

    const int N = in_sizes[0] / D;      // 100000
    const int E = in_sizes[2] / 2;      // 1200000

    float* out  = (float*)d_out;
    float* wzux = (float*)d_ws;         // N*D floats = 25.6 MB

    // d_out doubles as the scatter accumulator; zero it each call.
    hipMemsetAsync(out, 0, (size_t)N * D * sizeof(float), stream);

    wzux_kernel<<<1024, 256, 0, stream>>>(z, x, nf, W, Uw, Ub, wzux, N);

    int edge_blocks = (E * 16 + 255) / 256;
    edge_kernel<<<edge_blocks, 256, 0, stream>>>(
        (const float4*)wzux, ei, ei + E, nf,
        (const float4*)gamma, (const float4*)beta, out, E);

    out_kernel<<<1024, 256, 0, stream>>>(out, z, W, out, N);
}

// Round 2
// 698.176 us; speedup vs baseline: 3.2408x; 3.2408x over previous
//
#include <hip/hip_runtime.h>

#define D 64
#define LN_EPS 1e-5f
#define ALPHA 0.5f

// ---------------- Stage 1: WzUx = nf * (z@W.T + deg*(x@U.T + Ub)) ----------
__global__ __launch_bounds__(256) void wzux_kernel(
    const float* __restrict__ z, const float* __restrict__ x,
    const float* __restrict__ nf, const float* __restrict__ W,
    const float* __restrict__ Uw, const float* __restrict__ Ub,
    float* __restrict__ wzux, int N)
{
    __shared__ float Wsm[D * 65];
    __shared__ float Usm[D * 65];
    for (int i = threadIdx.x; i < D * D; i += blockDim.x) {
        Wsm[(i >> 6) * 65 + (i & 63)] = W[i];
        Usm[(i >> 6) * 65 + (i & 63)] = Uw[i];
    }
    __syncthreads();

    const int lane = threadIdx.x & 63;
    const int wid  = threadIdx.x >> 6;
    const float ub = Ub[lane];
    const float* wr = &Wsm[lane * 65];
    const float* ur = &Usm[lane * 65];

    for (int n = blockIdx.x * 4 + wid; n < N; n += gridDim.x * 4) {
        float nfv = nf[n];
        float deg = (nfv > 0.f) ? (1.f / nfv) : 0.f;
        float zv = z[n * D + lane];
        float xv = x[n * D + lane];
        float accw = 0.f, accu = 0.f;
#pragma unroll
        for (int k = 0; k < D; ++k) {
            float zk = __shfl(zv, k);
            float xk = __shfl(xv, k);
            accw = fmaf(zk, wr[k], accw);
            accu = fmaf(xk, ur[k], accu);
        }
        wzux[n * D + lane] = nfv * (accw + deg * (accu + ub));
    }
}

// ---------------- CSR build -----------------------------------------------
__global__ __launch_bounds__(256) void count_deg_kernel(
    const int* __restrict__ row, const int* __restrict__ col,
    int* __restrict__ deg, int E)
{
    int i = blockIdx.x * blockDim.x + threadIdx.x;
    if (i < E) {
        atomicAdd(&deg[row[i]], 1);
        atomicAdd(&deg[col[i]], 1);
    }
}

// per-block exclusive scan of degrees; blockSums[b] = block total
__global__ __launch_bounds__(256) void scan_block_kernel(
    const int* __restrict__ deg, int* __restrict__ rowptr,
    int* __restrict__ blockSums, int N)
{
    __shared__ int sm[256];
    int t = threadIdx.x;
    int i = blockIdx.x * 256 + t;
    int v = (i < N) ? deg[i] : 0;
    sm[t] = v;
    __syncthreads();
#pragma unroll
    for (int off = 1; off < 256; off <<= 1) {
        int add = (t >= off) ? sm[t - off] : 0;
        __syncthreads();
        sm[t] += add;
        __syncthreads();
    }
    if (i < N) rowptr[i] = sm[t] - v;           // exclusive within block
    if (t == 255) blockSums[blockIdx.x] = sm[255];
}

// single-block exclusive scan of blockSums (NB <= 1024)
__global__ __launch_bounds__(1024) void scan_sums_kernel(
    int* __restrict__ blockSums, int NB)
{
    __shared__ int sm[1024];
    int t = threadIdx.x;
    int v = (t < NB) ? blockSums[t] : 0;
    sm[t] = v;
    __syncthreads();
#pragma unroll
    for (int off = 1; off < 1024; off <<= 1) {
        int add = (t >= off) ? sm[t - off] : 0;
        __syncthreads();
        sm[t] += add;
        __syncthreads();
    }
    if (t < NB) blockSums[t] = sm[t] - v;       // exclusive
}

__global__ __launch_bounds__(256) void add_offsets_kernel(
    int* __restrict__ rowptr, int* __restrict__ cursor,
    const int* __restrict__ blockSums, int N)
{
    int i = blockIdx.x * 256 + threadIdx.x;
    if (i < N) {
        int v = rowptr[i] + blockSums[blockIdx.x];
        rowptr[i] = v;
        cursor[i] = v;
    }
}

// adj entry: (other_node << 1) | is_col_role
__global__ __launch_bounds__(256) void fill_adj_kernel(
    const int* __restrict__ row, const int* __restrict__ col,
    int* __restrict__ cursor, int* __restrict__ adj, int E)
{
    int i = blockIdx.x * blockDim.x + threadIdx.x;
    if (i < E) {
        int r = row[i], c = col[i];
        adj[atomicAdd(&cursor[r], 1)] = (c << 1);
        adj[atomicAdd(&cursor[c], 1)] = (r << 1) | 1;
    }
}

// ---------------- Node-centric aggregation (no f32 atomics) ----------------
// One wave per node; 4 incident edges processed in parallel by 16-lane
// groups. Each group recomputes relu+LayerNorm for its edge and accumulates
// signed contributions into per-lane float4 registers; groups are reduced
// across at the end with 2 shuffle steps. Output row stored once, coalesced.
__global__ __launch_bounds__(256) void agg_kernel(
    const float4* __restrict__ wzux4,
    const int* __restrict__ rowptr, const int* __restrict__ adj,
    const float* __restrict__ nf,
    const float4* __restrict__ gamma4, const float4* __restrict__ beta4,
    float4* __restrict__ out4, int N, int twoE)
{
    const int lane = threadIdx.x & 63;
    const int wid  = threadIdx.x >> 6;
    const int n = blockIdx.x * 4 + wid;
    if (n >= N) return;

    const int g = lane >> 4;    // edge slot within wave
    const int l = lane & 15;    // float4 slot within row

    const int s = rowptr[n];
    const int e = (n + 1 < N) ? rowptr[n + 1] : twoE;

    const float4 self = wzux4[n * 16 + l];
    const float4 gm = gamma4[l];
    const float4 bt = beta4[l];

    float4 acc = make_float4(0.f, 0.f, 0.f, 0.f);

    for (int base = s; base < e; base += 4) {
        int i = base + g;
        bool act = (i < e);
        int p = act ? adj[i] : 0;
        int other = p >> 1;
        float sgn = (p & 1) ? -1.f : 1.f;
        float4 o = act ? wzux4[other * 16 + l] : self;

        float r0 = fmaxf(sgn * (self.x - o.x), 0.f);
        float r1 = fmaxf(sgn * (self.y - o.y), 0.f);
        float r2 = fmaxf(sgn * (self.z - o.z), 0.f);
        float r3 = fmaxf(sgn * (self.w - o.w), 0.f);

        float ss = r0 + r1 + r2 + r3;
        float sq = r0 * r0 + r1 * r1 + r2 * r2 + r3 * r3;
#pragma unroll
        for (int off = 1; off < 16; off <<= 1) {
            ss += __shfl_xor(ss, off);
            sq += __shfl_xor(sq, off);
        }
        float mu   = ss * (1.f / 64.f);
        float var  = sq * (1.f / 64.f) - mu * mu;
        float rstd = rsqrtf(var + LN_EPS);

        if (act) {
            acc.x += sgn * ((r0 - mu) * rstd * gm.x + bt.x);
            acc.y += sgn * ((r1 - mu) * rstd * gm.y + bt.y);
            acc.z += sgn * ((r2 - mu) * rstd * gm.z + bt.z);
            acc.w += sgn * ((r3 - mu) * rstd * gm.w + bt.w);
        }
    }

    // reduce the 4 edge-slots (lanes g=0..3 hold partial sums for slot l)
#pragma unroll
    for (int m = 16; m < 64; m <<= 1) {
        acc.x += __shfl_xor(acc.x, m);
        acc.y += __shfl_xor(acc.y, m);
        acc.z += __shfl_xor(acc.z, m);
        acc.w += __shfl_xor(acc.w, m);
    }

    if (g == 0) {
        float nfv = nf[n];
        out4[n * 16 + l] = make_float4(acc.x * nfv, acc.y * nfv,
                                       acc.z * nfv, acc.w * nfv);
    }
}

// ---------------- Stage 3: out = ALPHA*(-(newz@W)) + (1-ALPHA)*z ----------
// In-place on d_out: each wave reads only its own row before storing it.
__global__ __launch_bounds__(256) void out_kernel(
    const float* __restrict__ accv, const float* __restrict__ z,
    const float* __restrict__ W, float* __restrict__ out, int N)
{
    __shared__ float Wsm[D * 65];
    for (int i = threadIdx.x; i < D * D; i += blockDim.x) {
        Wsm[(i >> 6) * 65 + (i & 63)] = W[i];
    }
    __syncthreads();

    const int lane = threadIdx.x & 63;
    const int wid  = threadIdx.x >> 6;

    for (int n = blockIdx.x * 4 + wid; n < N; n += gridDim.x * 4) {
        float nv = accv[n * D + lane];
        float acc = 0.f;
#pragma unroll
        for (int k = 0; k < D; ++k) {
            float nk = __shfl(nv, k);
            acc = fmaf(nk, Wsm[k * 65 + lane], acc);
        }
        out[n * D + lane] = (1.0f - ALPHA) * z[n * D + lane] - ALPHA * acc;
    }
}

extern "C" void kernel_launch(void* const* d_in, const int* in_sizes, int n_in,
                              void* d_out, int out_size, void* d_ws, size_t ws_size,
                              hipStream_t stream) {
    const float* z     = (const float*)d_in[0];
    const float* x     = (const float*)d_in[1];
    const int*   ei    = (const int*)d_in[2];
    const float* nf    = (const float*)d_in[3];
    const float* W     = (const float*)d_in[4];
    const float* Uw    = (const float*)d_in[5];
    const float* Ub    = (const float*)d_in[6];
    const float* gamma = (const float*)d_in[7];
    const float* beta  = (const float*)d_in[8];

    const int N = in_sizes[0] / D;      // 100000
    const int E = in_sizes[2] / 2;      // 1200000
    const int twoE = 2 * E;
    const int NB = (N + 255) / 256;     // scan blocks (<=1024 supported)

    float* out = (float*)d_out;

    // ---- workspace layout (256B-aligned segments) ----
    char* ws = (char*)d_ws;
    size_t off = 0;
    auto alloc = [&](size_t bytes) {
        char* p = ws + off;
        off += (bytes + 255) & ~(size_t)255;
        return p;
    };
    float* wzux      = (float*)alloc((size_t)N * D * sizeof(float)); // 25.6 MB
    int*   deg       = (int*)  alloc((size_t)N * sizeof(int));
    int*   rowptr    = (int*)  alloc((size_t)N * sizeof(int));
    int*   cursor    = (int*)  alloc((size_t)N * sizeof(int));
    int*   blockSums = (int*)  alloc((size_t)NB * sizeof(int));
    int*   adj       = (int*)  alloc((size_t)twoE * sizeof(int));    // 9.6 MB

    // ---- CSR build ----
    hipMemsetAsync(deg, 0, (size_t)N * sizeof(int), stream);
    int eb = (E + 255) / 256;
    count_deg_kernel<<<eb, 256, 0, stream>>>(ei, ei + E, deg, E);
    scan_block_kernel<<<NB, 256, 0, stream>>>(deg, rowptr, blockSums, N);
    scan_sums_kernel<<<1, 1024, 0, stream>>>(blockSums, NB);
    add_offsets_kernel<<<NB, 256, 0, stream>>>(rowptr, cursor, blockSums, N);
    fill_adj_kernel<<<eb, 256, 0, stream>>>(ei, ei + E, cursor, adj, E);

    // ---- node transform ----
    wzux_kernel<<<1024, 256, 0, stream>>>(z, x, nf, W, Uw, Ub, wzux, N);

    // ---- node-centric edge aggregation (writes d_out rows directly) ----
    int ab = (N + 3) / 4;
    agg_kernel<<<ab, 256, 0, stream>>>(
        (const float4*)wzux, rowptr, adj, nf,
        (const float4*)gamma, (const float4*)beta,
        (float4*)out, N, twoE);

    // ---- output transform (in place) ----
    out_kernel<<<1024, 256, 0, stream>>>(out, z, W, out, N);
}